// Round 7
// baseline (128.758 us; speedup 1.0000x reference)
//
#include <hip/hip_runtime.h>

// FullRelPos: out[b,hw,g, kh*32+kw] = attn[...] + lh[kh] + lw[kw]
//   lh[k] = dot(q[row, 0:32],  rel_emb_h[k-h+31, :])
//   lw[k] = dot(q[row,32:64],  rel_emb_w[k-w+31, :])
//
// Fused, one wave per (b,hw) task (8 g-rows = 32KB stream).
// R6 lesson: fill-shaped split-stream also capped ~5.1 TB/s -> scatter is not
// the limiter. This round's single-variable A/B vs R5: PLAIN stores instead of
// nontemporal (fill hits 7 TB/s with plain stores; nt gave no FETCH benefit:
// 139 vs 145 MB).

#define QL 1024    // H*W

__global__ __launch_bounds__(256) void relpos_fused3_kernel(
    const float* __restrict__ q,
    const float* __restrict__ attn,
    const float* __restrict__ reh,
    const float* __restrict__ rew,
    float* __restrict__ out,
    int ntasks)
{
    const int lane = threadIdx.x & 63;
    const int wid  = blockIdx.x * 4 + (threadIdx.x >> 6);
    const int nwaves = gridDim.x * 4;

    for (int t = wid; t < ntasks; t += nwaves) {
        const int hw = t & (QL - 1);         // task = (b, hw); 8 g-rows per task
        const int h  = hw >> 5;
        const int w  = hw & 31;
        const size_t r0 = (size_t)t << 3;

        // ---- logits: lanes 0..31 own lh[k], lanes 32..63 own lw[k] ----
        const int k = lane & 31;
        const float4* e4 = (lane < 32)
            ? (const float4*)(reh + (size_t)(k - h + 31) * 32)
            : (const float4*)(rew + (size_t)(k - w + 31) * 32);
        const float* qbase = q + r0 * 64 + (lane & 32);

        float acc[8];
        #pragma unroll
        for (int g = 0; g < 8; ++g) acc[g] = 0.f;
        #pragma unroll
        for (int c4 = 0; c4 < 8; ++c4) {
            const float4 ev = e4[c4];
            #pragma unroll
            for (int g = 0; g < 8; ++g) {
                const float4 qv = *(const float4*)(qbase + g * 64 + c4 * 4);
                acc[g] += qv.x * ev.x + qv.y * ev.y + qv.z * ev.z + qv.w * ev.w;
            }
        }

        // ---- redistribute ALL logits up front (no shfls in the stream loop) ----
        // lane's float4 unit u = lane + 64*j: kh = lane/8 + 8j, kw0 = (4*lane)&31
        const int kw0 = (lane << 2) & 31;
        const int kh0 = lane >> 3;
        float lh[8][4], lw[8][4];
        #pragma unroll
        for (int g = 0; g < 8; ++g) {
            const float a = acc[g];
            lh[g][0] = __shfl(a, kh0,      64);
            lh[g][1] = __shfl(a, kh0 + 8,  64);
            lh[g][2] = __shfl(a, kh0 + 16, 64);
            lh[g][3] = __shfl(a, kh0 + 24, 64);
            lw[g][0] = __shfl(a, 32 + kw0,     64);
            lw[g][1] = __shfl(a, 32 + kw0 + 1, 64);
            lw[g][2] = __shfl(a, 32 + kw0 + 2, 64);
            lw[g][3] = __shfl(a, 32 + kw0 + 3, 64);
        }

        // ---- stream: 2-deep double-buffered loads, PLAIN stores ----
        const float4* abase = (const float4*)(attn + r0 * QL);
        float4*       obase = (float4*)(out  + r0 * QL);

        float4 buf[2][4];
        #pragma unroll
        for (int j = 0; j < 4; ++j)
            buf[0][j] = abase[lane + 64 * j];

        #pragma unroll
        for (int g = 0; g < 8; ++g) {
            if (g < 7) {
                const float4* anext = abase + (size_t)(g + 1) * 256;
                #pragma unroll
                for (int j = 0; j < 4; ++j)
                    buf[(g + 1) & 1][j] = anext[lane + 64 * j];
            }
            float4* orow = obase + (size_t)g * 256;
            #pragma unroll
            for (int j = 0; j < 4; ++j) {
                const float4 a = buf[g & 1][j];
                const float tl = lh[g][j];
                float4 o;
                o.x = a.x + tl + lw[g][0];
                o.y = a.y + tl + lw[g][1];
                o.z = a.z + tl + lw[g][2];
                o.w = a.w + tl + lw[g][3];
                orow[lane + 64 * j] = o;
            }
        }
    }
}

extern "C" void kernel_launch(void* const* d_in, const int* in_sizes, int n_in,
                              void* d_out, int out_size, void* d_ws, size_t ws_size,
                              hipStream_t stream) {
    const float* q    = (const float*)d_in[0];
    const float* attn = (const float*)d_in[1];
    const float* reh  = (const float*)d_in[2];
    const float* rew  = (const float*)d_in[3];
    float* out = (float*)d_out;

    const int nrows  = in_sizes[1] / QL;   // B * QL * G = 65536
    const int ntasks = nrows >> 3;         // 8192 -> one per wave
    relpos_fused3_kernel<<<2048, 256, 0, stream>>>(q, attn, reh, rew, out, ntasks);
}

// Round 8
// 115.216 us; speedup vs baseline: 1.1175x; 1.1175x over previous
//
#include <hip/hip_runtime.h>

// FullRelPos: out[b,hw,g, kh*32+kw] = attn[...] + lh[kh] + lw[kw]
//   lh[k] = dot(q[row, 0:32],  rel_emb_h[k-h+31, :])
//   lw[k] = dot(q[row,32:64],  rel_emb_w[k-w+31, :])
//
// Fused, one wave per (b,hw) task (8 g-rows = 32KB stream).
// R7 A/B: nt stores beat plain by 17us (write-allocate evicted the read
// stream). This round: attn loads ALSO nontemporal — reads stop allocating
// in L2/L3, writes get the whole cache path; HBM has headroom (3.7 of 6.3).

#define QL 1024    // H*W

typedef float floatx4 __attribute__((ext_vector_type(4)));

__global__ __launch_bounds__(256) void relpos_fused4_kernel(
    const float* __restrict__ q,
    const float* __restrict__ attn,
    const float* __restrict__ reh,
    const float* __restrict__ rew,
    float* __restrict__ out,
    int ntasks)
{
    const int lane = threadIdx.x & 63;
    const int wid  = blockIdx.x * 4 + (threadIdx.x >> 6);
    const int nwaves = gridDim.x * 4;

    for (int t = wid; t < ntasks; t += nwaves) {
        const int hw = t & (QL - 1);         // task = (b, hw); 8 g-rows per task
        const int h  = hw >> 5;
        const int w  = hw & 31;
        const size_t r0 = (size_t)t << 3;

        // ---- logits: lanes 0..31 own lh[k], lanes 32..63 own lw[k] ----
        const int k = lane & 31;
        const float4* e4 = (lane < 32)
            ? (const float4*)(reh + (size_t)(k - h + 31) * 32)
            : (const float4*)(rew + (size_t)(k - w + 31) * 32);
        const float* qbase = q + r0 * 64 + (lane & 32);

        float acc[8];
        #pragma unroll
        for (int g = 0; g < 8; ++g) acc[g] = 0.f;
        #pragma unroll
        for (int c4 = 0; c4 < 8; ++c4) {
            const float4 ev = e4[c4];
            #pragma unroll
            for (int g = 0; g < 8; ++g) {
                const float4 qv = *(const float4*)(qbase + g * 64 + c4 * 4);
                acc[g] += qv.x * ev.x + qv.y * ev.y + qv.z * ev.z + qv.w * ev.w;
            }
        }

        // ---- redistribute ALL logits up front (no shfls in the stream loop) ----
        // lane's float4 unit u = lane + 64*j: kh = lane/8 + 8j, kw0 = (4*lane)&31
        const int kw0 = (lane << 2) & 31;
        const int kh0 = lane >> 3;
        float lh[8][4], lw[8][4];
        #pragma unroll
        for (int g = 0; g < 8; ++g) {
            const float a = acc[g];
            lh[g][0] = __shfl(a, kh0,      64);
            lh[g][1] = __shfl(a, kh0 + 8,  64);
            lh[g][2] = __shfl(a, kh0 + 16, 64);
            lh[g][3] = __shfl(a, kh0 + 24, 64);
            lw[g][0] = __shfl(a, 32 + kw0,     64);
            lw[g][1] = __shfl(a, 32 + kw0 + 1, 64);
            lw[g][2] = __shfl(a, 32 + kw0 + 2, 64);
            lw[g][3] = __shfl(a, 32 + kw0 + 3, 64);
        }

        // ---- stream: nt loads + nt stores, 2-deep double-buffered ----
        const floatx4* abase = (const floatx4*)(attn + r0 * QL);
        floatx4*       obase = (floatx4*)(out  + r0 * QL);

        floatx4 buf[2][4];
        #pragma unroll
        for (int j = 0; j < 4; ++j)
            buf[0][j] = __builtin_nontemporal_load(abase + lane + 64 * j);

        #pragma unroll
        for (int g = 0; g < 8; ++g) {
            if (g < 7) {
                const floatx4* anext = abase + (size_t)(g + 1) * 256;
                #pragma unroll
                for (int j = 0; j < 4; ++j)
                    buf[(g + 1) & 1][j] =
                        __builtin_nontemporal_load(anext + lane + 64 * j);
            }
            floatx4* orow = obase + (size_t)g * 256;
            #pragma unroll
            for (int j = 0; j < 4; ++j) {
                const floatx4 a = buf[g & 1][j];
                const float tl = lh[g][j];
                floatx4 o;
                o.x = a.x + tl + lw[g][0];
                o.y = a.y + tl + lw[g][1];
                o.z = a.z + tl + lw[g][2];
                o.w = a.w + tl + lw[g][3];
                __builtin_nontemporal_store(o, &orow[lane + 64 * j]);
            }
        }
    }
}

extern "C" void kernel_launch(void* const* d_in, const int* in_sizes, int n_in,
                              void* d_out, int out_size, void* d_ws, size_t ws_size,
                              hipStream_t stream) {
    const float* q    = (const float*)d_in[0];
    const float* attn = (const float*)d_in[1];
    const float* reh  = (const float*)d_in[2];
    const float* rew  = (const float*)d_in[3];
    float* out = (float*)d_out;

    const int nrows  = in_sizes[1] / QL;   // B * QL * G = 65536
    const int ntasks = nrows >> 3;         // 8192 -> one per wave
    relpos_fused4_kernel<<<2048, 256, 0, stream>>>(q, attn, reh, rew, out, ntasks);
}